// Round 15
// baseline (734.702 us; speedup 1.0000x reference)
//
#include <hip/hip_runtime.h>
#include <hip/hip_bf16.h>

#define NCLS 1000
#define BIMG 256
#define LSEQ 12
#define PFX  5
#define DMOD 512
#define NHEAD 8
#define NLAY 2
#define DFF  2048
#define DHEAD 64
#define ROWSPAD 12032

typedef __attribute__((ext_vector_type(8))) short bf16x8;
typedef __attribute__((ext_vector_type(4))) float f32x4;

__device__ __forceinline__ float gelu_fast(float x) {
    // tanh-gelu == x * sigmoid(2c(x + 0.044715 x^3)), 2c = 1.5957691216; exact identity
    float i = 1.5957691216f * (x + 0.044715f * x * x * x);
    return x / (1.0f + __expf(-i));
}

__device__ __forceinline__ float bf2f(unsigned short u) {
    unsigned int x = ((unsigned int)u) << 16;
    float f; __builtin_memcpy(&f, &x, 4); return f;
}

__device__ __forceinline__ short f2bf_s(float f) {
    __hip_bfloat16 h = __float2bfloat16(f);
    short s; __builtin_memcpy(&s, &h, 2); return s;
}

__device__ __forceinline__ void gload_lds16(const void* g, void* l) {
    __builtin_amdgcn_global_load_lds(
        (const __attribute__((address_space(1))) void*)g,
        (__attribute__((address_space(3))) void*)l, 16, 0, 0);
}

// ---------------- bf16 MFMA GEMM: TMx128 tile, 2-buffer, XCD bn-fast, chunk-XOR swizzle ----
// C = A(MxK bf16, row-major) @ B (Bt = N x K bf16 row-major)
// TM=256 (512 thr, 8 waves): 33% fewer staged bytes/FLOP for the big-grid GEMMs (R15).
// TM=128 (256 thr, 4 waves): R9-proven BK=64 config for narrow-N GEMMs.
// Swizzle involution on stage SOURCE and LDS READ (rule 21). 0 bank conflicts (R8+).
// Epilogue (EPI!=3): C-through-LDS transpose -> bf16x8 vector stores (R10-proven).
// EPI: 0=+bias->bf16 ; 2=+bias,+Rb(bf16) [+row-stat partials if psum] ;
//      3=exp(ls)*sM*sN->f32 ; 4=LN-fold from psum ; 5=LN-fold+gelu
// psum layout: float2 psum[4][ROWSPAD] = per-(row, N-panel) (sum, sumsq) of bf16 x.
template <int EPI, int BK, int TM>
__global__ __launch_bounds__(TM == 256 ? 512 : 256) void gemm_mfma(
    const __hip_bfloat16* __restrict__ A, int lda,
    const __hip_bfloat16* __restrict__ Bt, int ldb,
    const float* __restrict__ bias,            // EPI4/5: b2 vector
    const __hip_bfloat16* __restrict__ Rb, int ldr,
    float* __restrict__ Cf, int ldcf,
    __hip_bfloat16* __restrict__ Cb, int ldcb,
    int M, int K, int Nreal,
    const float* __restrict__ scaleM,
    const float* __restrict__ scaleN,
    const float* __restrict__ lsp,
    float2* __restrict__ psum,                 // EPI2: write; EPI4/5: read
    const float* __restrict__ s1v)             // EPI4/5 colsum(g*W)
{
    constexpr int THREADS = (TM == 256) ? 512 : 256;
    constexpr int ABUF = TM * BK;              // elements per A buffer
    constexpr int BBUF = 128 * BK;             // elements per B buffer
    __shared__ __align__(16) char smem[2 * ABUF * 2 + 2 * BBUF * 2];
    unsigned short* As0 = (unsigned short*)smem;
    unsigned short* Bs0 = (unsigned short*)(smem + 2 * ABUF * 2);

    const int t    = threadIdx.x;
    const int wid  = t >> 6, lane = t & 63;
    const int wm   = wid >> 1, wn = wid & 1;   // TM=256: wm 0..3 ; TM=128: wm 0..1
    const int lr   = lane & 15, lk = lane >> 4;

    // m204 bijective XCD chunking; bn FAST within a chunk (R6-proven: FETCH 97->23 MB)
    const unsigned int gx = gridDim.x, gy = gridDim.y;
    const unsigned int nwg = gx * gy;
    const unsigned int orig = blockIdx.y * gx + blockIdx.x;
    const unsigned int q8 = nwg >> 3, r8 = nwg & 7;
    const unsigned int xcd = orig & 7, slot = orig >> 3;
    const unsigned int wgid = (xcd < r8 ? xcd * (q8 + 1) : r8 * (q8 + 1) + (xcd - r8) * q8) + slot;
    const int bn = (int)(wgid % gx) * 128;
    const int bm = (int)(wgid / gx) * TM;

    f32x4 acc[4][4] = {};

    const __hip_bfloat16* Abase = A  + (size_t)bm * lda;
    const __hip_bfloat16* Bbase = Bt + (size_t)bn * ldb;

    // stage-side addressing
    const int srow32 = t >> 2;                                   // 0..THREADS/4-1
    const int cg32   = (((t & 3) ^ ((srow32 >> 1) & 3))) * 8;
    const int srow64 = t >> 3;                                   // BK=64: 0..31
    const int cg64   = (((t & 7) ^ (srow64 & 7))) * 8;

    auto STAGE = [&](int k0, int buf) {
        char* ab = (char*)(As0 + buf * ABUF);
        char* bb = (char*)(Bs0 + buf * BBUF);
        if constexpr (BK == 32) {
            // A tile TM x 32: 2 loads (rows srow32, srow32 + THREADS/4)
            gload_lds16(Abase + (size_t)srow32 * lda + k0 + cg32, ab + wid * 1024);
            gload_lds16(Abase + (size_t)(srow32 + THREADS / 4) * lda + k0 + cg32,
                        ab + THREADS * 16 + wid * 1024);
            if constexpr (THREADS == 512) {
                // B tile 128 x 32: single load, srow32 covers 0..127
                gload_lds16(Bbase + (size_t)srow32 * ldb + k0 + cg32, bb + wid * 1024);
            } else {
                gload_lds16(Bbase + (size_t)srow32 * ldb + k0 + cg32, bb + wid * 1024);
                gload_lds16(Bbase + (size_t)(srow32 + 64) * ldb + k0 + cg32, bb + 4096 + wid * 1024);
            }
        } else {
            #pragma unroll
            for (int p = 0; p < 4; p++) {
                gload_lds16(Abase + (size_t)(srow64 + p * 32) * lda + k0 + cg64,
                            ab + p * 4096 + wid * 1024);
                gload_lds16(Bbase + (size_t)(srow64 + p * 32) * ldb + k0 + cg64,
                            bb + p * 4096 + wid * 1024);
            }
        }
    };

    const int NIT = K / BK;
    STAGE(0, 0);
    asm volatile("s_waitcnt vmcnt(0)" ::: "memory");
    __builtin_amdgcn_s_barrier();

    int cur = 0;
    for (int it = 0; it < NIT; it++) {
        if (it + 1 < NIT) STAGE((it + 1) * BK, cur ^ 1);   // prefetch next tile over MFMA

        const unsigned short* Ac = As0 + cur * ABUF;
        const unsigned short* Bc = Bs0 + cur * BBUF;
        if constexpr (BK == 32) {
            const int swz = (lr >> 1) & 3;   // row-key: (wm*64+i*16+lr)>>1 & 3 == (lr>>1)&3
            bf16x8 a[4], b[4];
            #pragma unroll
            for (int i = 0; i < 4; i++)
                a[i] = *reinterpret_cast<const bf16x8*>(
                    &Ac[(wm * 64 + i * 16 + lr) * 32 + ((lk ^ swz) << 3)]);
            #pragma unroll
            for (int j = 0; j < 4; j++)
                b[j] = *reinterpret_cast<const bf16x8*>(
                    &Bc[(wn * 64 + j * 16 + lr) * 32 + ((lk ^ swz) << 3)]);
            #pragma unroll
            for (int i = 0; i < 4; i++)
                #pragma unroll
                for (int j = 0; j < 4; j++)
                    acc[i][j] = __builtin_amdgcn_mfma_f32_16x16x32_bf16(a[i], b[j], acc[i][j], 0, 0, 0);
        } else {
            const int key = lr & 7;
            bf16x8 a[4][2], b[4][2];
            #pragma unroll
            for (int i = 0; i < 4; i++)
                #pragma unroll
                for (int ks = 0; ks < 2; ks++)
                    a[i][ks] = *reinterpret_cast<const bf16x8*>(
                        &Ac[(wm * 64 + i * 16 + lr) * 64 + ((((ks << 2) | lk) ^ key) << 3)]);
            #pragma unroll
            for (int j = 0; j < 4; j++)
                #pragma unroll
                for (int ks = 0; ks < 2; ks++)
                    b[j][ks] = *reinterpret_cast<const bf16x8*>(
                        &Bc[(wn * 64 + j * 16 + lr) * 64 + ((((ks << 2) | lk) ^ key) << 3)]);
            #pragma unroll
            for (int i = 0; i < 4; i++)
                #pragma unroll
                for (int j = 0; j < 4; j++) {
                    acc[i][j] = __builtin_amdgcn_mfma_f32_16x16x32_bf16(a[i][0], b[j][0], acc[i][j], 0, 0, 0);
                    acc[i][j] = __builtin_amdgcn_mfma_f32_16x16x32_bf16(a[i][1], b[j][1], acc[i][j], 0, 0, 0);
                }
        }

        asm volatile("s_waitcnt vmcnt(0)" ::: "memory");
        __builtin_amdgcn_s_barrier();
        cur ^= 1;
    }

    if constexpr (EPI == 3) {
        // small logits GEMM: scalar path (C/D layout m89: col=lane&15, row=(lane>>4)*4+reg)
        const float lsv = expf(lsp[0]);
        #pragma unroll
        for (int i = 0; i < 4; i++) {
            int gm0 = bm + wm * 64 + i * 16 + lk * 4;
            #pragma unroll
            for (int j = 0; j < 4; j++) {
                int gn = bn + wn * 64 + j * 16 + lr;
                #pragma unroll
                for (int q = 0; q < 4; q++) {
                    int gm = gm0 + q;
                    if (gm >= M || gn >= Nreal) continue;
                    Cf[(size_t)gm * ldcf + gn] = lsv * scaleM[gm] * scaleN[gn] * acc[i][j][q];
                }
            }
        }
        return;
    }

    // ---- epilogue via LDS transpose: scatter fragments, read back row-major, bf16x8 stores ----
    __syncthreads();                       // staging LDS now reusable
    float* eb = (float*)smem;              // [TM/4][132] f32 (padded)
    const int c8 = t & 15;                 // 8-col chunk
    #pragma unroll
    for (int i = 0; i < 4; i++) {
        #pragma unroll
        for (int j = 0; j < 4; j++)
            #pragma unroll
            for (int q = 0; q < 4; q++)
                eb[(wm * 16 + lk * 4 + q) * 132 + wn * 64 + j * 16 + lr] = acc[i][j][q];
        __syncthreads();
        #pragma unroll
        for (int p = 0; p < 2; p++) {
            const int ebrow = p * (THREADS / 16) + (t >> 4);
            const int gm = bm + (ebrow >> 4) * 64 + i * 16 + (ebrow & 15);
            const int gn = bn + c8 * 8;
            const float* ep = &eb[ebrow * 132 + c8 * 8];
            float4 e0 = *(const float4*)ep;
            float4 e1 = *(const float4*)(ep + 4);
            float v[8] = {e0.x, e0.y, e0.z, e0.w, e1.x, e1.y, e1.z, e1.w};
            if (EPI == 4 || EPI == 5) {
                const int gms = gm < M ? gm : (M - 1);
                float2 p0 = psum[gms];
                float2 p1 = psum[ROWSPAD + gms];
                float2 p2 = psum[2 * ROWSPAD + gms];
                float2 p3 = psum[3 * ROWSPAD + gms];
                float muv = (p0.x + p1.x + p2.x + p3.x) * (1.0f / DMOD);
                float rsv = rsqrtf((p0.y + p1.y + p2.y + p3.y) * (1.0f / DMOD)
                                   - muv * muv + 1e-5f);
                const float crw = -muv * rsv;
                float4 s0 = *(const float4*)&s1v[gn];
                float4 s1 = *(const float4*)&s1v[gn + 4];
                float4 b0 = *(const float4*)&bias[gn];
                float4 b1 = *(const float4*)&bias[gn + 4];
                float sv[8] = {s0.x, s0.y, s0.z, s0.w, s1.x, s1.y, s1.z, s1.w};
                float bv[8] = {b0.x, b0.y, b0.z, b0.w, b1.x, b1.y, b1.z, b1.w};
                #pragma unroll
                for (int e = 0; e < 8; e++) v[e] = rsv * v[e] + crw * sv[e] + bv[e];
                if (EPI == 5) {
                    #pragma unroll
                    for (int e = 0; e < 8; e++) v[e] = gelu_fast(v[e]);
                }
            } else {
                if (bias) {
                    float4 b0 = *(const float4*)&bias[gn];
                    float4 b1 = *(const float4*)&bias[gn + 4];
                    v[0] += b0.x; v[1] += b0.y; v[2] += b0.z; v[3] += b0.w;
                    v[4] += b1.x; v[5] += b1.y; v[6] += b1.z; v[7] += b1.w;
                }
                if (EPI == 2) {
                    bf16x8 rv = *reinterpret_cast<const bf16x8*>(
                        &((const unsigned short*)Rb)[(size_t)gm * ldr + gn]);
                    #pragma unroll
                    for (int e = 0; e < 8; e++) v[e] += bf2f((unsigned short)rv[e]);
                }
            }
            bf16x8 o8;
            #pragma unroll
            for (int e = 0; e < 8; e++) o8[e] = f2bf_s(v[e]);
            if (gm < M)
                *reinterpret_cast<bf16x8*>(&((unsigned short*)Cb)[(size_t)gm * ldcb + gn]) = o8;
            if (EPI == 2) {
                // row-stat partials of the bf16-rounded output (feeds next LN-fold GEMM)
                if (psum) {
                    float ls = 0.f, lq = 0.f;
                    #pragma unroll
                    for (int e = 0; e < 8; e++) {
                        float vv = bf2f((unsigned short)o8[e]);
                        ls += vv; lq += vv * vv;
                    }
                    #pragma unroll
                    for (int off = 1; off < 16; off <<= 1) {
                        ls += __shfl_xor(ls, off, 64);
                        lq += __shfl_xor(lq, off, 64);
                    }
                    if (c8 == 0 && gm < M) {
                        float2 pv; pv.x = ls; pv.y = lq;
                        psum[(bn >> 7) * ROWSPAD + gm] = pv;
                    }
                }
            }
        }
        __syncthreads();
    }
}

// ---------------- batched weight transpose + f32->bf16, folding LN gain g into Wqkv/W1 ----
__global__ __launch_bounds__(256) void transpose_all(
    const float* __restrict__ Wqkv, const float* __restrict__ Wo,
    const float* __restrict__ W1,   const float* __restrict__ W2,
    const float* __restrict__ tproj,
    const float* __restrict__ g1,   const float* __restrict__ g2,
    __hip_bfloat16* __restrict__ wT, __hip_bfloat16* __restrict__ tprojT)
{
    const size_t LS = (size_t)(3 * DMOD) * DMOD + (size_t)DMOD * DMOD
                    + (size_t)DMOD * DFF + (size_t)DFF * DMOD;
    int bid = blockIdx.x;
    const float* W; __hip_bfloat16* Wt; int rows, cols, rb;
    const float* gfold = nullptr;
    if (bid < 2 * 3072) {
        int l = bid / 3072, r = bid % 3072;
        __hip_bfloat16* base = wT + (size_t)l * LS;
        if (r < 768) {
            W = Wqkv + (size_t)l * DMOD * 3 * DMOD; Wt = base;
            rows = DMOD; cols = 3 * DMOD; rb = r; gfold = g1 + l * DMOD;
        } else if (r < 1024) {
            W = Wo + (size_t)l * DMOD * DMOD; Wt = base + (size_t)(3 * DMOD) * DMOD;
            rows = DMOD; cols = DMOD; rb = r - 768;
        } else if (r < 2048) {
            W = W1 + (size_t)l * DMOD * DFF;
            Wt = base + (size_t)(3 * DMOD) * DMOD + (size_t)DMOD * DMOD;
            rows = DMOD; cols = DFF; rb = r - 1024; gfold = g2 + l * DMOD;
        } else {
            W = W2 + (size_t)l * DFF * DMOD;
            Wt = base + (size_t)(3 * DMOD) * DMOD + (size_t)DMOD * DMOD + (size_t)DMOD * DFF;
            rows = DFF; cols = DMOD; rb = r - 2048;
        }
    } else {
        W = tproj; Wt = tprojT; rows = DMOD; cols = DMOD; rb = bid - 6144;
    }
    const int cb = cols >> 5;
    const int bc = (rb % cb) * 32, br = (rb / cb) * 32;

    __shared__ float tile[32][33];
    const int tx = threadIdx.x & 31, ty = threadIdx.x >> 5;
    #pragma unroll
    for (int i = 0; i < 4; i++) {
        int r = ty + i * 8;
        tile[r][tx] = W[(size_t)(br + r) * cols + bc + tx];
    }
    __syncthreads();
    const float gv = gfold ? gfold[br + tx] : 1.0f;   // d-index = br+tx on write side
    #pragma unroll
    for (int i = 0; i < 4; i++) {
        int r = ty + i * 8;
        Wt[(size_t)(bc + r) * rows + br + tx] = __float2bfloat16(tile[tx][r] * gv);
    }
}

// ---------------- LN-fold vector prep, stage 1: partial colsums over d-slices ----------------
__global__ __launch_bounds__(256) void prep_part(
    const float* __restrict__ Wqkv, const float* __restrict__ W1,
    const float* __restrict__ g1, const float* __restrict__ c1b,
    const float* __restrict__ g2, const float* __restrict__ c2b,
    float2* __restrict__ pp)    // pp[s][7168] = (g.W, lnb.W)
{
    const int c = blockIdx.x, s = blockIdx.y;
    const float* W; const float* g; const float* lnb; int cols, n, flat;
    if (c < 6)       { W = Wqkv;                                cols = 1536; g = g1;        lnb = c1b;        n = c * 256;        flat = n; }
    else if (c < 12) { W = Wqkv + (size_t)DMOD * 1536;          cols = 1536; g = g1 + DMOD; lnb = c1b + DMOD; n = (c - 6) * 256;  flat = 1536 + n; }
    else if (c < 20) { W = W1;                                  cols = 2048; g = g2;        lnb = c2b;        n = (c - 12) * 256; flat = 3072 + n; }
    else             { W = W1 + (size_t)DMOD * 2048;            cols = 2048; g = g2 + DMOD; lnb = c2b + DMOD; n = (c - 20) * 256; flat = 5120 + n; }
    n += threadIdx.x; flat += threadIdx.x;
    float sg = 0.f, sb = 0.f;
    const int d0 = s * 64;
    for (int d = d0; d < d0 + 64; d++) {
        float w = W[(size_t)d * cols + n];
        sg += g[d] * w;
        sb += lnb[d] * w;
    }
    float2 o; o.x = sg; o.y = sb;
    pp[(size_t)s * 7168 + flat] = o;
}

// ---------------- LN-fold vector prep, stage 2: combine slices ----------------
__global__ __launch_bounds__(256) void prep_comb(
    const float2* __restrict__ pp,
    const float* __restrict__ bqkv, const float* __restrict__ b1,
    float* __restrict__ s1qkv, float* __restrict__ b2qkv,
    float* __restrict__ s1ff1, float* __restrict__ b2ff1)
{
    const int c = blockIdx.x;
    int flat = c * 256 + threadIdx.x;
    float sg = 0.f, sb = 0.f;
    #pragma unroll
    for (int s = 0; s < 8; s++) {
        float2 p = pp[(size_t)s * 7168 + flat];
        sg += p.x; sb += p.y;
    }
    if (flat < 3072) {
        int l = flat / 1536, n = flat % 1536;
        s1qkv[flat] = sg;
        b2qkv[flat] = bqkv[(size_t)l * 1536 + n] + sb;
    } else {
        int f2 = flat - 3072;
        int l = f2 / 2048, n = f2 % 2048;
        s1ff1[f2] = sg;
        b2ff1[f2] = b1[(size_t)l * 2048 + n] + sb;
    }
}

// ---------------- adjust (raw [*attr]) -> x bf16 + row-stat partials ----------------
__global__ __launch_bounds__(256) void adjust_stats(
    const float* __restrict__ raw, const float* __restrict__ attr,
    __hip_bfloat16* __restrict__ x, float2* __restrict__ psum)
{
    const int lane = threadIdx.x & 63;
    const int r = blockIdx.x * 4 + (threadIdx.x >> 6);
    const int l = r % LSEQ, n = r / LSEQ;
    const float sc = (attr != nullptr && l < PFX) ? attr[n * PFX + l] : 1.0f;
    const float4* xr = (const float4*)(raw + (size_t)r * DMOD);
    float4 u = xr[lane * 2], v = xr[lane * 2 + 1];
    float f[8] = {u.x * sc, u.y * sc, u.z * sc, u.w * sc,
                  v.x * sc, v.y * sc, v.z * sc, v.w * sc};
    bf16x8 x8;
    #pragma unroll
    for (int e = 0; e < 8; e++) x8[e] = f2bf_s(f[e]);
    *reinterpret_cast<bf16x8*>(&x[(size_t)r * DMOD + lane * 8]) = x8;
    // stats on the bf16-rounded values (matches what the GEMM consumes)
    float s = 0.f, qq = 0.f;
    #pragma unroll
    for (int e = 0; e < 8; e++) { float ff = bf2f((unsigned short)x8[e]); s += ff; qq += ff * ff; }
    #pragma unroll
    for (int off = 32; off > 0; off >>= 1) {
        s  += __shfl_xor(s,  off, 64);
        qq += __shfl_xor(qq, off, 64);
    }
    if (lane == 0) {
        float2 pv; pv.x = s; pv.y = qq;
        psum[r] = pv;
        float2 z; z.x = 0.f; z.y = 0.f;
        psum[ROWSPAD + r] = z;
        psum[2 * ROWSPAD + r] = z;
        psum[3 * ROWSPAD + r] = z;
    }
}

// ---------------- inverse L2 row norm, bf16 input ----------------
__global__ __launch_bounds__(256) void rownorm_inv_bf16(
    const __hip_bfloat16* __restrict__ x, float* __restrict__ inv)
{
    const int r = blockIdx.x, t = threadIdx.x;
    const unsigned short* xr = (const unsigned short*)(x + (size_t)r * DMOD);
    float v0 = bf2f(xr[t]), v1 = bf2f(xr[t + 256]);
    __shared__ float rq[256];
    rq[t] = v0 * v0 + v1 * v1;
    __syncthreads();
    for (int off = 128; off > 0; off >>= 1) {
        if (t < off) rq[t] += rq[t + off];
        __syncthreads();
    }
    if (t == 0) inv[r] = rsqrtf(rq[0]);
}

// ---------------- final prep: images->bf16 + inv-norm (wave-per-row), tf pad zero ----------------
__global__ __launch_bounds__(256) void final_prep2(
    const float* __restrict__ images,
    __hip_bfloat16* __restrict__ img_bf, float* __restrict__ invi,
    __hip_bfloat16* __restrict__ tf_bf)
{
    const int bid = blockIdx.x;
    if (bid < 64) {
        const int lane = threadIdx.x & 63;
        const int r = bid * 4 + (threadIdx.x >> 6);
        const float4* xr = (const float4*)(images + (size_t)r * DMOD);
        float4 u = xr[lane * 2], v = xr[lane * 2 + 1];
        float f[8] = {u.x, u.y, u.z, u.w, v.x, v.y, v.z, v.w};
        bf16x8 o8;
        float qq = 0.f;
        #pragma unroll
        for (int e = 0; e < 8; e++) { o8[e] = f2bf_s(f[e]); qq += f[e] * f[e]; }
        *reinterpret_cast<bf16x8*>(&img_bf[(size_t)r * DMOD + lane * 8]) = o8;
        #pragma unroll
        for (int off = 32; off > 0; off >>= 1) qq += __shfl_xor(qq, off, 64);
        if (lane == 0) invi[r] = rsqrtf(qq);
    } else {
        int idx = (bid - 64) * 256 + threadIdx.x;   // 0..1535
        bf16x8 z = {};
        *reinterpret_cast<bf16x8*>(&tf_bf[(size_t)NCLS * DMOD + idx * 8]) = z;
    }
}

// ---------------- fused attention: block = one class n ----------------
__global__ __launch_bounds__(256) void attn_fused(
    const __hip_bfloat16* __restrict__ qkv,
    __hip_bfloat16* __restrict__ out,
    float* __restrict__ plast)
{
    const int n = blockIdx.x, t = threadIdx.x;
    __shared__ __hip_bfloat16 S[12][1544];
    __shared__ float P[8][12][13];

    const __hip_bfloat16* src = qkv + (size_t)n * LSEQ * (3 * DMOD);
    for (int c = t; c < 12 * 192; c += 256) {
        int r = c / 192, col = (c % 192) * 8;
        *reinterpret_cast<bf16x8*>(&S[r][col]) =
            *reinterpret_cast<const bf16x8*>(&src[(size_t)r * (3 * DMOD) + col]);
    }
    __syncthreads();

    const int h = t >> 5, l32 = t & 31;
    if (l32 < LSEQ) {
        const int qi = l32;
        float sc[LSEQ];
        #pragma unroll
        for (int ki = 0; ki < LSEQ; ki++) {
            float acc = 0.f;
            #pragma unroll
            for (int d = 0; d < DHEAD; d += 8) {
                bf16x8 qv = *reinterpret_cast<const bf16x8*>(&S[qi][h * 64 + d]);
                bf16x8 kv = *reinterpret_cast<const bf16x8*>(&S[ki][512 + h * 64 + d]);
                #pragma unroll
                for (int e = 0; e < 8; e++)
                    acc += bf2f((unsigned short)qv[e]) * bf2f((unsigned short)kv[e]);
            }
            sc[ki] = acc * 0.125f + (ki > qi ? -1e9f : 0.f);
        }
        float m = sc[0];
        #pragma unroll
        for (int ki = 1; ki < LSEQ; ki++) m = fmaxf(m, sc[ki]);
        float e[LSEQ], s = 0.f;
        #pragma unroll
        for (int ki = 0; ki < LSEQ; ki++) { e[ki] = expf(sc[ki] - m); s += e[ki]; }
        float rcp = 1.0f / s;
        #pragma unroll
        for (int ki = 0; ki < LSEQ; ki++) P[h][qi][ki] = e[ki] * rcp;
        if (qi == LSEQ - 1) {
            #pragma unroll
            for (int ki = 0; ki < LSEQ; ki++)
                plast[((size_t)n * NHEAD + h) * LSEQ + ki] = e[ki] * rcp;
        }
    }
    __syncthreads();

    #pragma unroll
    for (int dd = 0; dd < 2; dd++) {
        int d = l32 * 2 + dd;
        for (int qi = 0; qi < LSEQ; qi++) {
            float acc = 0.f;
            #pragma unroll
            for (int ki = 0; ki < LSEQ; ki++)
                acc += P[h][qi][ki] * bf2f(((const unsigned short*)&S[ki][1024 + h * 64])[d]);
            out[((size_t)(n * LSEQ + qi)) * DMOD + h * 64 + d] = __float2bfloat16(acc);
        }
    }
}

// ---------------- attr from plast ----------------
__global__ __launch_bounds__(256) void attr_kernel(
    const float* __restrict__ plast, float* __restrict__ attr)
{
    int n = blockIdx.x * 256 + threadIdx.x;
    if (n >= NCLS) return;
    float a[PFX]; float s = 0.f;
    #pragma unroll
    for (int p = 0; p < PFX; p++) {
        float acc = 0.f;
        for (int hh = 0; hh < NHEAD; hh++)
            acc += plast[((size_t)n * NHEAD + hh) * LSEQ + p];
        a[p] = acc * (1.0f / NHEAD);
        s += a[p];
    }
    #pragma unroll
    for (int p = 0; p < PFX; p++) attr[n * PFX + p] = a[p] / (s + 1e-8f);
}

// ---------------- attribution output ----------------
__global__ __launch_bounds__(256) void attribution_kernel(
    const float* __restrict__ attr, float* __restrict__ out2)
{
    int p = blockIdx.x, t = threadIdx.x;
    float s = 0.f;
    for (int n = t; n < NCLS; n += 256) s += attr[n * PFX + p];
    __shared__ float rq[256];
    rq[t] = s; __syncthreads();
    for (int off = 128; off > 0; off >>= 1) {
        if (t < off) rq[t] += rq[t + off];
        __syncthreads();
    }
    float mean = rq[0] * (1.0f / NCLS);
    out2[t * PFX + p] = mean;
}

extern "C" void kernel_launch(void* const* d_in, const int* in_sizes, int n_in,
                              void* d_out, int out_size, void* d_ws, size_t ws_size,
                              hipStream_t stream)
{
    const float* images = (const float*)d_in[0];
    const float* raw    = (const float*)d_in[1];
    const float* Wqkv   = (const float*)d_in[2];
    const float* bqkv   = (const float*)d_in[3];
    const float* Wo     = (const float*)d_in[4];
    const float* bo     = (const float*)d_in[5];
    const float* W1     = (const float*)d_in[6];
    const float* b1     = (const float*)d_in[7];
    const float* W2     = (const float*)d_in[8];
    const float* b2     = (const float*)d_in[9];
    const float* g1     = (const float*)d_in[10];
    const float* c1     = (const float*)d_in[11];
    const float* g2     = (const float*)d_in[12];
    const float* c2v    = (const float*)d_in[13];
    const float* tproj  = (const float*)d_in[14];
    const float* lsp    = (const float*)d_in[15];
    float* out = (float*)d_out;

    const int ROWS = NCLS * LSEQ;    // 12000

    // ---- workspace: fp32 region, then bf16 region ----
    float* ws    = (float*)d_ws;
    float* plast = ws;                                     // 1000*8*12
    float* attr  = plast + (size_t)NCLS * NHEAD * LSEQ;    // 5120 (padded)
    float* invi  = attr + 5120;                            // 512
    float* invt  = invi + 512;                             // 1024
    float2* psum = (float2*)(invt + 1024);                 // 4*12032 float2
    float2* pp   = psum + 4 * ROWSPAD;                     // 8*7168 float2
    float* s1qkv = (float*)(pp + 8 * 7168);                // 2*1536
    float* b2qkv = s1qkv + 2 * 3 * DMOD;                   // 2*1536
    float* s1ff1 = b2qkv + 2 * 3 * DMOD;                   // 2*2048
    float* b2ff1 = s1ff1 + 2 * DFF;                        // 2*2048
    __hip_bfloat16* x      = (__hip_bfloat16*)(b2ff1 + 2 * DFF);
    __hip_bfloat16* h_bf   = x + (size_t)ROWSPAD * DMOD;            // 12032*512
    __hip_bfloat16* u_bf   = h_bf + (size_t)ROWSPAD * DMOD;         // 12032*2048
    __hip_bfloat16* wT     = u_bf + (size_t)ROWSPAD * DFF;
    const size_t LS = (size_t)(3 * DMOD) * DMOD + (size_t)DMOD * DMOD
                    + (size_t)DMOD * DFF + (size_t)DFF * DMOD;
    __hip_bfloat16* tprojT = wT + NLAY * LS;                        // 512*512
    __hip_bfloat16* img_bf = tprojT + (size_t)DMOD * DMOD;          // 256*512
    __hip_bfloat16* tf_bf  = img_bf + (size_t)BIMG * DMOD;          // 1024*512

    // weight transposes (g folded into Wqkv/W1) + LN-fold vectors (2-stage parallel)
    transpose_all<<<6400, 256, 0, stream>>>(Wqkv, Wo, W1, W2, tproj, g1, g2, wT, tprojT);
    prep_part<<<dim3(28, 8), 256, 0, stream>>>(Wqkv, W1, g1, c1, g2, c2v, pp);
    prep_comb<<<28, 256, 0, stream>>>(pp, bqkv, b1, s1qkv, b2qkv, s1ff1, b2ff1);

    auto run_pass = [&](bool useAttr) {
        for (int l = 0; l < NLAY; l++) {
            __hip_bfloat16* wqkvT = wT + l * LS;
            __hip_bfloat16* woT   = wqkvT + (size_t)(3 * DMOD) * DMOD;
            __hip_bfloat16* w1T   = woT + (size_t)DMOD * DMOD;
            __hip_bfloat16* w2T   = w1T + (size_t)DMOD * DFF;

            if (l == 0)
                adjust_stats<<<ROWS / 4, 256, 0, stream>>>(
                    raw, useAttr ? attr : nullptr, x, psum);
            // qkv = LN1(x) @ Wqkv + bqkv, folded (EPI=4, BK=32, TM=256, 512 thr)
            gemm_mfma<4, 32, 256><<<dim3(12, 47), 512, 0, stream>>>(
                x, DMOD, wqkvT, DMOD, b2qkv + l * 3 * DMOD,
                nullptr, 0, nullptr, 0, u_bf, 3 * DMOD, ROWS, DMOD,
                3 * DMOD, nullptr, nullptr, nullptr,
                psum, s1qkv + l * 3 * DMOD);
            attn_fused<<<NCLS, 256, 0, stream>>>(u_bf, h_bf, plast);
            // x = x + attn_out @ Wo + bo (EPI=2, BK=64, TM=128) + row-stat partials for FF1
            gemm_mfma<2, 64, 128><<<dim3(4, 94), 256, 0, stream>>>(
                h_bf, DMOD, woT, DMOD, bo + l * DMOD,
                x, DMOD, nullptr, 0, x, DMOD, ROWS, DMOD,
                DMOD, nullptr, nullptr, nullptr, psum, nullptr);
            // g = gelu(LN2(x) @ W1 + b1), folded (EPI=5, BK=32, TM=256, 512 thr)
            gemm_mfma<5, 32, 256><<<dim3(16, 47), 512, 0, stream>>>(
                x, DMOD, w1T, DMOD, b2ff1 + l * DFF,
                nullptr, 0, nullptr, 0, u_bf, DFF, ROWS, DMOD,
                DFF, nullptr, nullptr, nullptr,
                psum, s1ff1 + l * DFF);
            // x = x + g @ W2 + b2 (EPI=2, BK=64, TM=128) + partials for next qkv (l=0 only)
            gemm_mfma<2, 64, 128><<<dim3(4, 94), 256, 0, stream>>>(
                u_bf, DFF, w2T, DFF, b2 + l * DMOD,
                x, DMOD, nullptr, 0, x, DMOD, ROWS, DFF,
                DMOD, nullptr, nullptr, nullptr,
                (l == 0) ? psum : nullptr, nullptr);
        }
    };

    run_pass(false);
    attr_kernel<<<4, 256, 0, stream>>>(plast, attr);
    run_pass(true);

    // final head
    final_prep2<<<70, 256, 0, stream>>>(images, img_bf, invi, tf_bf);
    // tf = x2[:, -1, :] @ tproj (A = x strided by 12 rows; overflow reads land in
    // adjacent workspace, writes guarded by gm<M)
    gemm_mfma<0, 64, 128><<<dim3(4, 8), 256, 0, stream>>>(
        x + 11 * DMOD, LSEQ * DMOD, tprojT, DMOD, nullptr,
        nullptr, 0, nullptr, 0, tf_bf, DMOD, NCLS, DMOD,
        DMOD, nullptr, nullptr, nullptr, nullptr, nullptr);
    rownorm_inv_bf16<<<NCLS, 256, 0, stream>>>(tf_bf, invt);
    // logits = exp(ls) * invi[m] * invt[n] * (img_bf @ tf_bf^T)
    gemm_mfma<3, 64, 128><<<dim3(8, 2), 256, 0, stream>>>(
        img_bf, DMOD, tf_bf, DMOD, nullptr,
        nullptr, 0, out, NCLS, nullptr, 0, BIMG, DMOD,
        NCLS, invi, invt, lsp, nullptr, nullptr);
    attribution_kernel<<<PFX, 256, 0, stream>>>(attr, out + (size_t)BIMG * NCLS);
}

// Round 16
// 527.270 us; speedup vs baseline: 1.3934x; 1.3934x over previous
//
#include <hip/hip_runtime.h>
#include <hip/hip_bf16.h>

#define NCLS 1000
#define BIMG 256
#define LSEQ 12
#define PFX  5
#define DMOD 512
#define NHEAD 8
#define NLAY 2
#define DFF  2048
#define DHEAD 64
#define ROWSPAD 12032

typedef __attribute__((ext_vector_type(8))) short bf16x8;
typedef __attribute__((ext_vector_type(4))) float f32x4;

__device__ __forceinline__ float gelu_fast(float x) {
    // tanh-gelu == x * sigmoid(2c(x + 0.044715 x^3)), 2c = 1.5957691216; exact identity
    float i = 1.5957691216f * (x + 0.044715f * x * x * x);
    return x / (1.0f + __expf(-i));
}

__device__ __forceinline__ float bf2f(unsigned short u) {
    unsigned int x = ((unsigned int)u) << 16;
    float f; __builtin_memcpy(&f, &x, 4); return f;
}

__device__ __forceinline__ short f2bf_s(float f) {
    __hip_bfloat16 h = __float2bfloat16(f);
    short s; __builtin_memcpy(&s, &h, 2); return s;
}

__device__ __forceinline__ void gload_lds16(const void* g, void* l) {
    __builtin_amdgcn_global_load_lds(
        (const __attribute__((address_space(1))) void*)g,
        (__attribute__((address_space(3))) void*)l, 16, 0, 0);
}

// ---------------- bf16 MFMA GEMM: 128x128, 2-buffer, XCD bn-fast, chunk-XOR swizzle ----
// C = A(MxK bf16, row-major) @ B (Bt = N x K bf16 row-major)
// BK=32 / BK=64 per R9/R11 findings. Swizzle involution both sides (rule 21), 0 conflicts.
// Epilogue (EPI!=3): C-through-LDS transpose -> bf16x8 vector stores (R10-proven).
// EPI: 0=+bias->bf16 ; 2=+bias,+Rb(bf16) [+row-stat partials if psum] ;
//      3=exp(ls)*sM*sN->f32 ; 4=LN-fold from psum ; 5=LN-fold+gelu
// psum layout: float2 psum[4][ROWSPAD] = per-(row, N-panel) (sum, sumsq) of bf16 x.
template <int EPI, int BK>
__global__ __launch_bounds__(256) void gemm_mfma(
    const __hip_bfloat16* __restrict__ A, int lda,
    const __hip_bfloat16* __restrict__ Bt, int ldb,
    const float* __restrict__ bias,            // EPI4/5: b2 vector
    const __hip_bfloat16* __restrict__ Rb, int ldr,
    float* __restrict__ Cf, int ldcf,
    __hip_bfloat16* __restrict__ Cb, int ldcb,
    int M, int K, int Nreal,
    const float* __restrict__ scaleM,
    const float* __restrict__ scaleN,
    const float* __restrict__ lsp,
    float2* __restrict__ psum,                 // EPI2: write; EPI4/5: read
    const float* __restrict__ s1v)             // EPI4/5 colsum(g*W)
{
    constexpr int STAGE_BYTES = 2 * 128 * BK * 2;          // 2 buffers, one matrix
    __shared__ __align__(16) char smem[2 * STAGE_BYTES];   // A region, then B region
    unsigned short* As0 = (unsigned short*)smem;           // [2][128*BK]
    unsigned short* Bs0 = (unsigned short*)(smem + STAGE_BYTES);

    const int t    = threadIdx.x;
    const int wid  = t >> 6, lane = t & 63;
    const int wm   = wid >> 1, wn = wid & 1;
    const int lr   = lane & 15, lk = lane >> 4;

    // m204 bijective XCD chunking; bn FAST within a chunk (R6-proven: FETCH 97->23 MB)
    const unsigned int gx = gridDim.x, gy = gridDim.y;
    const unsigned int nwg = gx * gy;
    const unsigned int orig = blockIdx.y * gx + blockIdx.x;
    const unsigned int q8 = nwg >> 3, r8 = nwg & 7;
    const unsigned int xcd = orig & 7, slot = orig >> 3;
    const unsigned int wgid = (xcd < r8 ? xcd * (q8 + 1) : r8 * (q8 + 1) + (xcd - r8) * q8) + slot;
    const int bn = (int)(wgid % gx) * 128;
    const int bm = (int)(wgid / gx) * 128;

    f32x4 acc[4][4] = {};

    const __hip_bfloat16* Abase = A  + (size_t)bm * lda;
    const __hip_bfloat16* Bbase = Bt + (size_t)bn * ldb;

    // stage-side addressing
    const int srow32 = t >> 2;                                   // BK=32: 0..63
    const int cg32   = (((t & 3) ^ ((srow32 >> 1) & 3))) * 8;
    const int srow64 = t >> 3;                                   // BK=64: 0..31
    const int cg64   = (((t & 7) ^ (srow64 & 7))) * 8;

    auto STAGE = [&](int k0, int buf) {
        char* ab = (char*)(As0 + buf * 128 * BK);
        char* bb = (char*)(Bs0 + buf * 128 * BK);
        if constexpr (BK == 32) {
            gload_lds16(Abase + (size_t)srow32        * lda + k0 + cg32, ab + wid * 1024);
            gload_lds16(Abase + (size_t)(srow32 + 64) * lda + k0 + cg32, ab + 4096 + wid * 1024);
            gload_lds16(Bbase + (size_t)srow32        * ldb + k0 + cg32, bb + wid * 1024);
            gload_lds16(Bbase + (size_t)(srow32 + 64) * ldb + k0 + cg32, bb + 4096 + wid * 1024);
        } else {
            #pragma unroll
            for (int p = 0; p < 4; p++) {
                gload_lds16(Abase + (size_t)(srow64 + p * 32) * lda + k0 + cg64,
                            ab + p * 4096 + wid * 1024);
                gload_lds16(Bbase + (size_t)(srow64 + p * 32) * ldb + k0 + cg64,
                            bb + p * 4096 + wid * 1024);
            }
        }
    };

    const int NIT = K / BK;
    STAGE(0, 0);
    asm volatile("s_waitcnt vmcnt(0)" ::: "memory");
    __builtin_amdgcn_s_barrier();

    int cur = 0;
    for (int it = 0; it < NIT; it++) {
        if (it + 1 < NIT) STAGE((it + 1) * BK, cur ^ 1);   // prefetch next tile over MFMA

        const unsigned short* Ac = As0 + cur * 128 * BK;
        const unsigned short* Bc = Bs0 + cur * 128 * BK;
        if constexpr (BK == 32) {
            const int swz = (lr >> 1) & 3;
            bf16x8 a[4], b[4];
            #pragma unroll
            for (int i = 0; i < 4; i++)
                a[i] = *reinterpret_cast<const bf16x8*>(
                    &Ac[(wm * 64 + i * 16 + lr) * 32 + ((lk ^ swz) << 3)]);
            #pragma unroll
            for (int j = 0; j < 4; j++)
                b[j] = *reinterpret_cast<const bf16x8*>(
                    &Bc[(wn * 64 + j * 16 + lr) * 32 + ((lk ^ swz) << 3)]);
            #pragma unroll
            for (int i = 0; i < 4; i++)
                #pragma unroll
                for (int j = 0; j < 4; j++)
                    acc[i][j] = __builtin_amdgcn_mfma_f32_16x16x32_bf16(a[i], b[j], acc[i][j], 0, 0, 0);
        } else {
            const int key = lr & 7;
            bf16x8 a[4][2], b[4][2];
            #pragma unroll
            for (int i = 0; i < 4; i++)
                #pragma unroll
                for (int ks = 0; ks < 2; ks++)
                    a[i][ks] = *reinterpret_cast<const bf16x8*>(
                        &Ac[(wm * 64 + i * 16 + lr) * 64 + ((((ks << 2) | lk) ^ key) << 3)]);
            #pragma unroll
            for (int j = 0; j < 4; j++)
                #pragma unroll
                for (int ks = 0; ks < 2; ks++)
                    b[j][ks] = *reinterpret_cast<const bf16x8*>(
                        &Bc[(wn * 64 + j * 16 + lr) * 64 + ((((ks << 2) | lk) ^ key) << 3)]);
            #pragma unroll
            for (int i = 0; i < 4; i++)
                #pragma unroll
                for (int j = 0; j < 4; j++) {
                    acc[i][j] = __builtin_amdgcn_mfma_f32_16x16x32_bf16(a[i][0], b[j][0], acc[i][j], 0, 0, 0);
                    acc[i][j] = __builtin_amdgcn_mfma_f32_16x16x32_bf16(a[i][1], b[j][1], acc[i][j], 0, 0, 0);
                }
        }

        asm volatile("s_waitcnt vmcnt(0)" ::: "memory");
        __builtin_amdgcn_s_barrier();
        cur ^= 1;
    }

    if constexpr (EPI == 3) {
        // small logits GEMM: scalar path (C/D layout m89: col=lane&15, row=(lane>>4)*4+reg)
        const float lsv = expf(lsp[0]);
        #pragma unroll
        for (int i = 0; i < 4; i++) {
            int gm0 = bm + wm * 64 + i * 16 + lk * 4;
            #pragma unroll
            for (int j = 0; j < 4; j++) {
                int gn = bn + wn * 64 + j * 16 + lr;
                #pragma unroll
                for (int q = 0; q < 4; q++) {
                    int gm = gm0 + q;
                    if (gm >= M || gn >= Nreal) continue;
                    Cf[(size_t)gm * ldcf + gn] = lsv * scaleM[gm] * scaleN[gn] * acc[i][j][q];
                }
            }
        }
        return;
    }

    // ---- epilogue via LDS transpose: scatter fragments, read back row-major, bf16x8 stores ----
    __syncthreads();                       // staging LDS now reusable
    float* eb = (float*)smem;              // [32][132] f32 (padded)
    const int row_r = t >> 4;              // 0..15
    const int c8    = t & 15;              // 8-col chunk
    #pragma unroll
    for (int i = 0; i < 4; i++) {
        #pragma unroll
        for (int j = 0; j < 4; j++)
            #pragma unroll
            for (int q = 0; q < 4; q++)
                eb[(wm * 16 + lk * 4 + q) * 132 + wn * 64 + j * 16 + lr] = acc[i][j][q];
        __syncthreads();
        #pragma unroll
        for (int half = 0; half < 2; half++) {
            const int gm = bm + half * 64 + i * 16 + row_r;
            const int gn = bn + c8 * 8;
            const float* ep = &eb[(half * 16 + row_r) * 132 + c8 * 8];
            float4 e0 = *(const float4*)ep;
            float4 e1 = *(const float4*)(ep + 4);
            float v[8] = {e0.x, e0.y, e0.z, e0.w, e1.x, e1.y, e1.z, e1.w};
            if (EPI == 4 || EPI == 5) {
                const int gms = gm < M ? gm : (M - 1);
                float2 p0 = psum[gms];
                float2 p1 = psum[ROWSPAD + gms];
                float2 p2 = psum[2 * ROWSPAD + gms];
                float2 p3 = psum[3 * ROWSPAD + gms];
                float muv = (p0.x + p1.x + p2.x + p3.x) * (1.0f / DMOD);
                float rsv = rsqrtf((p0.y + p1.y + p2.y + p3.y) * (1.0f / DMOD)
                                   - muv * muv + 1e-5f);
                const float crw = -muv * rsv;
                float4 s0 = *(const float4*)&s1v[gn];
                float4 s1 = *(const float4*)&s1v[gn + 4];
                float4 b0 = *(const float4*)&bias[gn];
                float4 b1 = *(const float4*)&bias[gn + 4];
                float sv[8] = {s0.x, s0.y, s0.z, s0.w, s1.x, s1.y, s1.z, s1.w};
                float bv[8] = {b0.x, b0.y, b0.z, b0.w, b1.x, b1.y, b1.z, b1.w};
                #pragma unroll
                for (int e = 0; e < 8; e++) v[e] = rsv * v[e] + crw * sv[e] + bv[e];
                if (EPI == 5) {
                    #pragma unroll
                    for (int e = 0; e < 8; e++) v[e] = gelu_fast(v[e]);
                }
            } else {
                if (bias) {
                    float4 b0 = *(const float4*)&bias[gn];
                    float4 b1 = *(const float4*)&bias[gn + 4];
                    v[0] += b0.x; v[1] += b0.y; v[2] += b0.z; v[3] += b0.w;
                    v[4] += b1.x; v[5] += b1.y; v[6] += b1.z; v[7] += b1.w;
                }
                if (EPI == 2) {
                    bf16x8 rv = *reinterpret_cast<const bf16x8*>(
                        &((const unsigned short*)Rb)[(size_t)gm * ldr + gn]);
                    #pragma unroll
                    for (int e = 0; e < 8; e++) v[e] += bf2f((unsigned short)rv[e]);
                }
            }
            bf16x8 o8;
            #pragma unroll
            for (int e = 0; e < 8; e++) o8[e] = f2bf_s(v[e]);
            if (gm < M)
                *reinterpret_cast<bf16x8*>(&((unsigned short*)Cb)[(size_t)gm * ldcb + gn]) = o8;
            if (EPI == 2) {
                // row-stat partials of the bf16-rounded output (feeds next LN-fold GEMM)
                if (psum) {
                    float ls = 0.f, lq = 0.f;
                    #pragma unroll
                    for (int e = 0; e < 8; e++) {
                        float vv = bf2f((unsigned short)o8[e]);
                        ls += vv; lq += vv * vv;
                    }
                    #pragma unroll
                    for (int off = 1; off < 16; off <<= 1) {
                        ls += __shfl_xor(ls, off, 64);
                        lq += __shfl_xor(lq, off, 64);
                    }
                    if (c8 == 0 && gm < M) {
                        float2 pv; pv.x = ls; pv.y = lq;
                        psum[(bn >> 7) * ROWSPAD + gm] = pv;
                    }
                }
            }
        }
        __syncthreads();
    }
}

// ---------------- batched weight transpose + f32->bf16, folding LN gain g into Wqkv/W1 ----
__global__ __launch_bounds__(256) void transpose_all(
    const float* __restrict__ Wqkv, const float* __restrict__ Wo,
    const float* __restrict__ W1,   const float* __restrict__ W2,
    const float* __restrict__ tproj,
    const float* __restrict__ g1,   const float* __restrict__ g2,
    __hip_bfloat16* __restrict__ wT, __hip_bfloat16* __restrict__ tprojT)
{
    const size_t LS = (size_t)(3 * DMOD) * DMOD + (size_t)DMOD * DMOD
                    + (size_t)DMOD * DFF + (size_t)DFF * DMOD;
    int bid = blockIdx.x;
    const float* W; __hip_bfloat16* Wt; int rows, cols, rb;
    const float* gfold = nullptr;
    if (bid < 2 * 3072) {
        int l = bid / 3072, r = bid % 3072;
        __hip_bfloat16* base = wT + (size_t)l * LS;
        if (r < 768) {
            W = Wqkv + (size_t)l * DMOD * 3 * DMOD; Wt = base;
            rows = DMOD; cols = 3 * DMOD; rb = r; gfold = g1 + l * DMOD;
        } else if (r < 1024) {
            W = Wo + (size_t)l * DMOD * DMOD; Wt = base + (size_t)(3 * DMOD) * DMOD;
            rows = DMOD; cols = DMOD; rb = r - 768;
        } else if (r < 2048) {
            W = W1 + (size_t)l * DMOD * DFF;
            Wt = base + (size_t)(3 * DMOD) * DMOD + (size_t)DMOD * DMOD;
            rows = DMOD; cols = DFF; rb = r - 1024; gfold = g2 + l * DMOD;
        } else {
            W = W2 + (size_t)l * DFF * DMOD;
            Wt = base + (size_t)(3 * DMOD) * DMOD + (size_t)DMOD * DMOD + (size_t)DMOD * DFF;
            rows = DFF; cols = DMOD; rb = r - 2048;
        }
    } else {
        W = tproj; Wt = tprojT; rows = DMOD; cols = DMOD; rb = bid - 6144;
    }
    const int cb = cols >> 5;
    const int bc = (rb % cb) * 32, br = (rb / cb) * 32;

    __shared__ float tile[32][33];
    const int tx = threadIdx.x & 31, ty = threadIdx.x >> 5;
    #pragma unroll
    for (int i = 0; i < 4; i++) {
        int r = ty + i * 8;
        tile[r][tx] = W[(size_t)(br + r) * cols + bc + tx];
    }
    __syncthreads();
    const float gv = gfold ? gfold[br + tx] : 1.0f;   // d-index = br+tx on write side
    #pragma unroll
    for (int i = 0; i < 4; i++) {
        int r = ty + i * 8;
        Wt[(size_t)(bc + r) * rows + br + tx] = __float2bfloat16(tile[tx][r] * gv);
    }
}

// ---------------- LN-fold vector prep, stage 1: partial colsums over d-slices ----------------
__global__ __launch_bounds__(256) void prep_part(
    const float* __restrict__ Wqkv, const float* __restrict__ W1,
    const float* __restrict__ g1, const float* __restrict__ c1b,
    const float* __restrict__ g2, const float* __restrict__ c2b,
    float2* __restrict__ pp)    // pp[s][7168] = (g.W, lnb.W)
{
    const int c = blockIdx.x, s = blockIdx.y;
    const float* W; const float* g; const float* lnb; int cols, n, flat;
    if (c < 6)       { W = Wqkv;                                cols = 1536; g = g1;        lnb = c1b;        n = c * 256;        flat = n; }
    else if (c < 12) { W = Wqkv + (size_t)DMOD * 1536;          cols = 1536; g = g1 + DMOD; lnb = c1b + DMOD; n = (c - 6) * 256;  flat = 1536 + n; }
    else if (c < 20) { W = W1;                                  cols = 2048; g = g2;        lnb = c2b;        n = (c - 12) * 256; flat = 3072 + n; }
    else             { W = W1 + (size_t)DMOD * 2048;            cols = 2048; g = g2 + DMOD; lnb = c2b + DMOD; n = (c - 20) * 256; flat = 5120 + n; }
    n += threadIdx.x; flat += threadIdx.x;
    float sg = 0.f, sb = 0.f;
    const int d0 = s * 64;
    for (int d = d0; d < d0 + 64; d++) {
        float w = W[(size_t)d * cols + n];
        sg += g[d] * w;
        sb += lnb[d] * w;
    }
    float2 o; o.x = sg; o.y = sb;
    pp[(size_t)s * 7168 + flat] = o;
}

// ---------------- LN-fold vector prep, stage 2: combine slices ----------------
__global__ __launch_bounds__(256) void prep_comb(
    const float2* __restrict__ pp,
    const float* __restrict__ bqkv, const float* __restrict__ b1,
    float* __restrict__ s1qkv, float* __restrict__ b2qkv,
    float* __restrict__ s1ff1, float* __restrict__ b2ff1)
{
    const int c = blockIdx.x;
    int flat = c * 256 + threadIdx.x;
    float sg = 0.f, sb = 0.f;
    #pragma unroll
    for (int s = 0; s < 8; s++) {
        float2 p = pp[(size_t)s * 7168 + flat];
        sg += p.x; sb += p.y;
    }
    if (flat < 3072) {
        int l = flat / 1536, n = flat % 1536;
        s1qkv[flat] = sg;
        b2qkv[flat] = bqkv[(size_t)l * 1536 + n] + sb;
    } else {
        int f2 = flat - 3072;
        int l = f2 / 2048, n = f2 % 2048;
        s1ff1[f2] = sg;
        b2ff1[f2] = b1[(size_t)l * 2048 + n] + sb;
    }
}

// ---------------- adjust (raw [*attr]) -> x bf16 + row-stat partials ----------------
__global__ __launch_bounds__(256) void adjust_stats(
    const float* __restrict__ raw, const float* __restrict__ attr,
    __hip_bfloat16* __restrict__ x, float2* __restrict__ psum)
{
    const int lane = threadIdx.x & 63;
    const int r = blockIdx.x * 4 + (threadIdx.x >> 6);
    const int l = r % LSEQ, n = r / LSEQ;
    const float sc = (attr != nullptr && l < PFX) ? attr[n * PFX + l] : 1.0f;
    const float4* xr = (const float4*)(raw + (size_t)r * DMOD);
    float4 u = xr[lane * 2], v = xr[lane * 2 + 1];
    float f[8] = {u.x * sc, u.y * sc, u.z * sc, u.w * sc,
                  v.x * sc, v.y * sc, v.z * sc, v.w * sc};
    bf16x8 x8;
    #pragma unroll
    for (int e = 0; e < 8; e++) x8[e] = f2bf_s(f[e]);
    *reinterpret_cast<bf16x8*>(&x[(size_t)r * DMOD + lane * 8]) = x8;
    float s = 0.f, qq = 0.f;
    #pragma unroll
    for (int e = 0; e < 8; e++) { float ff = bf2f((unsigned short)x8[e]); s += ff; qq += ff * ff; }
    #pragma unroll
    for (int off = 32; off > 0; off >>= 1) {
        s  += __shfl_xor(s,  off, 64);
        qq += __shfl_xor(qq, off, 64);
    }
    if (lane == 0) {
        float2 pv; pv.x = s; pv.y = qq;
        psum[r] = pv;
        float2 z; z.x = 0.f; z.y = 0.f;
        psum[ROWSPAD + r] = z;
        psum[2 * ROWSPAD + r] = z;
        psum[3 * ROWSPAD + r] = z;
    }
}

// ---------------- inverse L2 row norm, bf16 input ----------------
__global__ __launch_bounds__(256) void rownorm_inv_bf16(
    const __hip_bfloat16* __restrict__ x, float* __restrict__ inv)
{
    const int r = blockIdx.x, t = threadIdx.x;
    const unsigned short* xr = (const unsigned short*)(x + (size_t)r * DMOD);
    float v0 = bf2f(xr[t]), v1 = bf2f(xr[t + 256]);
    __shared__ float rq[256];
    rq[t] = v0 * v0 + v1 * v1;
    __syncthreads();
    for (int off = 128; off > 0; off >>= 1) {
        if (t < off) rq[t] += rq[t + off];
        __syncthreads();
    }
    if (t == 0) inv[r] = rsqrtf(rq[0]);
}

// ---------------- final prep: images->bf16 + inv-norm (wave-per-row), tf pad zero ----------------
__global__ __launch_bounds__(256) void final_prep2(
    const float* __restrict__ images,
    __hip_bfloat16* __restrict__ img_bf, float* __restrict__ invi,
    __hip_bfloat16* __restrict__ tf_bf)
{
    const int bid = blockIdx.x;
    if (bid < 64) {
        const int lane = threadIdx.x & 63;
        const int r = bid * 4 + (threadIdx.x >> 6);
        const float4* xr = (const float4*)(images + (size_t)r * DMOD);
        float4 u = xr[lane * 2], v = xr[lane * 2 + 1];
        float f[8] = {u.x, u.y, u.z, u.w, v.x, v.y, v.z, v.w};
        bf16x8 o8;
        float qq = 0.f;
        #pragma unroll
        for (int e = 0; e < 8; e++) { o8[e] = f2bf_s(f[e]); qq += f[e] * f[e]; }
        *reinterpret_cast<bf16x8*>(&img_bf[(size_t)r * DMOD + lane * 8]) = o8;
        #pragma unroll
        for (int off = 32; off > 0; off >>= 1) qq += __shfl_xor(qq, off, 64);
        if (lane == 0) invi[r] = rsqrtf(qq);
    } else {
        int idx = (bid - 64) * 256 + threadIdx.x;   // 0..1535
        bf16x8 z = {};
        *reinterpret_cast<bf16x8*>(&tf_bf[(size_t)NCLS * DMOD + idx * 8]) = z;
    }
}

// ---------------- fused attention (full): block = one class n (layer-0 passes) ----------------
__global__ __launch_bounds__(256) void attn_fused(
    const __hip_bfloat16* __restrict__ qkv,
    __hip_bfloat16* __restrict__ out,
    float* __restrict__ plast)
{
    const int n = blockIdx.x, t = threadIdx.x;
    __shared__ __hip_bfloat16 S[12][1544];
    __shared__ float P[8][12][13];

    const __hip_bfloat16* src = qkv + (size_t)n * LSEQ * (3 * DMOD);
    for (int c = t; c < 12 * 192; c += 256) {
        int r = c / 192, col = (c % 192) * 8;
        *reinterpret_cast<bf16x8*>(&S[r][col]) =
            *reinterpret_cast<const bf16x8*>(&src[(size_t)r * (3 * DMOD) + col]);
    }
    __syncthreads();

    const int h = t >> 5, l32 = t & 31;
    if (l32 < LSEQ) {
        const int qi = l32;
        float sc[LSEQ];
        #pragma unroll
        for (int ki = 0; ki < LSEQ; ki++) {
            float acc = 0.f;
            #pragma unroll
            for (int d = 0; d < DHEAD; d += 8) {
                bf16x8 qv = *reinterpret_cast<const bf16x8*>(&S[qi][h * 64 + d]);
                bf16x8 kv = *reinterpret_cast<const bf16x8*>(&S[ki][512 + h * 64 + d]);
                #pragma unroll
                for (int e = 0; e < 8; e++)
                    acc += bf2f((unsigned short)qv[e]) * bf2f((unsigned short)kv[e]);
            }
            sc[ki] = acc * 0.125f + (ki > qi ? -1e9f : 0.f);
        }
        float m = sc[0];
        #pragma unroll
        for (int ki = 1; ki < LSEQ; ki++) m = fmaxf(m, sc[ki]);
        float e[LSEQ], s = 0.f;
        #pragma unroll
        for (int ki = 0; ki < LSEQ; ki++) { e[ki] = expf(sc[ki] - m); s += e[ki]; }
        float rcp = 1.0f / s;
        #pragma unroll
        for (int ki = 0; ki < LSEQ; ki++) P[h][qi][ki] = e[ki] * rcp;
        if (qi == LSEQ - 1) {
            #pragma unroll
            for (int ki = 0; ki < LSEQ; ki++)
                plast[((size_t)n * NHEAD + h) * LSEQ + ki] = e[ki] * rcp;
        }
    }
    __syncthreads();

    #pragma unroll
    for (int dd = 0; dd < 2; dd++) {
        int d = l32 * 2 + dd;
        for (int qi = 0; qi < LSEQ; qi++) {
            float acc = 0.f;
            #pragma unroll
            for (int ki = 0; ki < LSEQ; ki++)
                acc += P[h][qi][ki] * bf2f(((const unsigned short*)&S[ki][1024 + h * 64])[d]);
            out[((size_t)(n * LSEQ + qi)) * DMOD + h * 64 + d] = __float2bfloat16(acc);
        }
    }
}

// ---------------- attn probs for LAST query row only -> plast (pass-1 layer-1) ----------------
__global__ __launch_bounds__(128) void attn_plast(
    const __hip_bfloat16* __restrict__ qkv, float* __restrict__ plast)
{
    const int n = blockIdx.x, t = threadIdx.x;
    __shared__ float sc[8][12];
    if (t < 96) {
        const int h = t / 12, ki = t % 12;
        const unsigned short* q = (const unsigned short*)qkv + (size_t)(n * LSEQ + 11) * 1536 + h * 64;
        const unsigned short* k = (const unsigned short*)qkv + (size_t)(n * LSEQ + ki) * 1536 + 512 + h * 64;
        float acc = 0.f;
        #pragma unroll
        for (int d = 0; d < DHEAD; d += 8) {
            bf16x8 qv = *reinterpret_cast<const bf16x8*>(&q[d]);
            bf16x8 kv = *reinterpret_cast<const bf16x8*>(&k[d]);
            #pragma unroll
            for (int e = 0; e < 8; e++)
                acc += bf2f((unsigned short)qv[e]) * bf2f((unsigned short)kv[e]);
        }
        sc[h][ki] = acc * 0.125f;     // qi=11: causal mask allows all 12 keys
    }
    __syncthreads();
    if (t < 8) {
        float m = sc[t][0];
        #pragma unroll
        for (int ki = 1; ki < 12; ki++) m = fmaxf(m, sc[t][ki]);
        float e[12], s = 0.f;
        #pragma unroll
        for (int ki = 0; ki < 12; ki++) { e[ki] = expf(sc[t][ki] - m); s += e[ki]; }
        float r = 1.0f / s;
        #pragma unroll
        for (int ki = 0; ki < 12; ki++)
            plast[((size_t)n * NHEAD + t) * LSEQ + ki] = e[ki] * r;
    }
}

// ---------------- attn out for LAST query row only -> compact [1024][512] (pass-2 layer-1) ----
__global__ __launch_bounds__(128) void attn_last(
    const __hip_bfloat16* __restrict__ qkv, __hip_bfloat16* __restrict__ outc)
{
    const int n = blockIdx.x, t = threadIdx.x;
    __shared__ float P[8][12];
    {
        __shared__ float sc[8][12];
        if (t < 96) {
            const int h = t / 12, ki = t % 12;
            const unsigned short* q = (const unsigned short*)qkv + (size_t)(n * LSEQ + 11) * 1536 + h * 64;
            const unsigned short* k = (const unsigned short*)qkv + (size_t)(n * LSEQ + ki) * 1536 + 512 + h * 64;
            float acc = 0.f;
            #pragma unroll
            for (int d = 0; d < DHEAD; d += 8) {
                bf16x8 qv = *reinterpret_cast<const bf16x8*>(&q[d]);
                bf16x8 kv = *reinterpret_cast<const bf16x8*>(&k[d]);
                #pragma unroll
                for (int e = 0; e < 8; e++)
                    acc += bf2f((unsigned short)qv[e]) * bf2f((unsigned short)kv[e]);
            }
            sc[h][ki] = acc * 0.125f;
        }
        __syncthreads();
        if (t < 8) {
            float m = sc[t][0];
            #pragma unroll
            for (int ki = 1; ki < 12; ki++) m = fmaxf(m, sc[t][ki]);
            float e[12], s = 0.f;
            #pragma unroll
            for (int ki = 0; ki < 12; ki++) { e[ki] = expf(sc[t][ki] - m); s += e[ki]; }
            float r = 1.0f / s;
            #pragma unroll
            for (int ki = 0; ki < 12; ki++) P[t][ki] = e[ki] * r;
        }
        __syncthreads();
    }
    // PV for qi=11: 128 threads x 4 dims
    #pragma unroll
    for (int e = 0; e < 4; e++) {
        const int d = t * 4 + e;          // 0..511
        const int h = d >> 6, dd = d & 63;
        float acc = 0.f;
        #pragma unroll
        for (int ki = 0; ki < 12; ki++)
            acc += P[h][ki] * bf2f(((const unsigned short*)qkv)
                       [(size_t)(n * LSEQ + ki) * 1536 + 1024 + h * 64 + dd]);
        outc[(size_t)n * DMOD + d] = __float2bfloat16(acc);
    }
}

// ---------------- attr from plast ----------------
__global__ __launch_bounds__(256) void attr_kernel(
    const float* __restrict__ plast, float* __restrict__ attr)
{
    int n = blockIdx.x * 256 + threadIdx.x;
    if (n >= NCLS) return;
    float a[PFX]; float s = 0.f;
    #pragma unroll
    for (int p = 0; p < PFX; p++) {
        float acc = 0.f;
        for (int hh = 0; hh < NHEAD; hh++)
            acc += plast[((size_t)n * NHEAD + hh) * LSEQ + p];
        a[p] = acc * (1.0f / NHEAD);
        s += a[p];
    }
    #pragma unroll
    for (int p = 0; p < PFX; p++) attr[n * PFX + p] = a[p] / (s + 1e-8f);
}

// ---------------- attribution output ----------------
__global__ __launch_bounds__(256) void attribution_kernel(
    const float* __restrict__ attr, float* __restrict__ out2)
{
    int p = blockIdx.x, t = threadIdx.x;
    float s = 0.f;
    for (int n = t; n < NCLS; n += 256) s += attr[n * PFX + p];
    __shared__ float rq[256];
    rq[t] = s; __syncthreads();
    for (int off = 128; off > 0; off >>= 1) {
        if (t < off) rq[t] += rq[t + off];
        __syncthreads();
    }
    float mean = rq[0] * (1.0f / NCLS);
    out2[t * PFX + p] = mean;
}

extern "C" void kernel_launch(void* const* d_in, const int* in_sizes, int n_in,
                              void* d_out, int out_size, void* d_ws, size_t ws_size,
                              hipStream_t stream)
{
    const float* images = (const float*)d_in[0];
    const float* raw    = (const float*)d_in[1];
    const float* Wqkv   = (const float*)d_in[2];
    const float* bqkv   = (const float*)d_in[3];
    const float* Wo     = (const float*)d_in[4];
    const float* bo     = (const float*)d_in[5];
    const float* W1     = (const float*)d_in[6];
    const float* b1     = (const float*)d_in[7];
    const float* W2     = (const float*)d_in[8];
    const float* b2     = (const float*)d_in[9];
    const float* g1     = (const float*)d_in[10];
    const float* c1     = (const float*)d_in[11];
    const float* g2     = (const float*)d_in[12];
    const float* c2v    = (const float*)d_in[13];
    const float* tproj  = (const float*)d_in[14];
    const float* lsp    = (const float*)d_in[15];
    float* out = (float*)d_out;

    const int ROWS = NCLS * LSEQ;    // 12000

    // ---- workspace: fp32 region, then bf16 region ----
    float* ws    = (float*)d_ws;
    float* plast = ws;                                     // 1000*8*12
    float* attr  = plast + (size_t)NCLS * NHEAD * LSEQ;    // 5120 (padded)
    float* invi  = attr + 5120;                            // 512
    float* invt  = invi + 512;                             // 1024
    float2* psum = (float2*)(invt + 1024);                 // 4*12032 float2
    float2* pp   = psum + 4 * ROWSPAD;                     // 8*7168 float2
    float* s1qkv = (float*)(pp + 8 * 7168);                // 2*1536
    float* b2qkv = s1qkv + 2 * 3 * DMOD;                   // 2*1536
    float* s1ff1 = b2qkv + 2 * 3 * DMOD;                   // 2*2048
    float* b2ff1 = s1ff1 + 2 * DFF;                        // 2*2048
    __hip_bfloat16* x      = (__hip_bfloat16*)(b2ff1 + 2 * DFF);
    __hip_bfloat16* h_bf   = x + (size_t)ROWSPAD * DMOD;            // 12032*512
    __hip_bfloat16* u_bf   = h_bf + (size_t)ROWSPAD * DMOD;         // 12032*2048
    __hip_bfloat16* wT     = u_bf + (size_t)ROWSPAD * DFF;
    const size_t LS = (size_t)(3 * DMOD) * DMOD + (size_t)DMOD * DMOD
                    + (size_t)DMOD * DFF + (size_t)DFF * DMOD;
    __hip_bfloat16* tprojT = wT + NLAY * LS;                        // 512*512
    __hip_bfloat16* img_bf = tprojT + (size_t)DMOD * DMOD;          // 256*512
    __hip_bfloat16* tf_bf  = img_bf + (size_t)BIMG * DMOD;          // 1024*512
    __hip_bfloat16* hl_bf  = tf_bf + (size_t)1024 * DMOD;           // 1024*512 (compact attn-out)
    __hip_bfloat16* xl_bf  = hl_bf + (size_t)1024 * DMOD;           // 1024*512 (compact residual)

    // weight transposes (g folded into Wqkv/W1) + LN-fold vectors (2-stage parallel)
    transpose_all<<<6400, 256, 0, stream>>>(Wqkv, Wo, W1, W2, tproj, g1, g2, wT, tprojT);
    prep_part<<<dim3(28, 8), 256, 0, stream>>>(Wqkv, W1, g1, c1, g2, c2v, pp);
    prep_comb<<<28, 256, 0, stream>>>(pp, bqkv, b1, s1qkv, b2qkv, s1ff1, b2ff1);

    const size_t LSo = (size_t)(3 * DMOD) * DMOD;   // offset of Wo in a layer block

    // ======================= PASS 1 (full layer 0; layer 1 only needs plast) ==========
    adjust_stats<<<ROWS / 4, 256, 0, stream>>>(raw, nullptr, x, psum);
    // layer 0 (full)
    gemm_mfma<4, 32><<<dim3(12, 94), 256, 0, stream>>>(
        x, DMOD, wT, DMOD, b2qkv, nullptr, 0, nullptr, 0, u_bf, 3 * DMOD,
        ROWS, DMOD, 3 * DMOD, nullptr, nullptr, nullptr, psum, s1qkv);
    attn_fused<<<NCLS, 256, 0, stream>>>(u_bf, h_bf, plast);
    gemm_mfma<2, 64><<<dim3(4, 94), 256, 0, stream>>>(
        h_bf, DMOD, wT + LSo, DMOD, bo, x, DMOD, nullptr, 0, x, DMOD,
        ROWS, DMOD, DMOD, nullptr, nullptr, nullptr, psum, nullptr);
    gemm_mfma<5, 32><<<dim3(16, 94), 256, 0, stream>>>(
        x, DMOD, wT + LSo + (size_t)DMOD * DMOD, DMOD, b2ff1, nullptr, 0, nullptr, 0,
        u_bf, DFF, ROWS, DMOD, DFF, nullptr, nullptr, nullptr, psum, s1ff1);
    gemm_mfma<2, 64><<<dim3(4, 94), 256, 0, stream>>>(
        u_bf, DFF, wT + LSo + (size_t)DMOD * DMOD + (size_t)DMOD * DFF, DFF, b2,
        x, DMOD, nullptr, 0, x, DMOD, ROWS, DFF, DMOD,
        nullptr, nullptr, nullptr, psum, nullptr);
    // layer 1: Q,K only (N=1024) + last-row probs
    gemm_mfma<4, 32><<<dim3(8, 94), 256, 0, stream>>>(
        x, DMOD, wT + LS, DMOD, b2qkv + 3 * DMOD, nullptr, 0, nullptr, 0,
        u_bf, 3 * DMOD, ROWS, DMOD, 1024, nullptr, nullptr, nullptr,
        psum, s1qkv + 3 * DMOD);
    attn_plast<<<NCLS, 128, 0, stream>>>(u_bf, plast);

    attr_kernel<<<4, 256, 0, stream>>>(plast, attr);

    // ======================= PASS 2 (full layer 0; layer 1 compact to last rows) ======
    adjust_stats<<<ROWS / 4, 256, 0, stream>>>(raw, attr, x, psum);
    // layer 0 (full)
    gemm_mfma<4, 32><<<dim3(12, 94), 256, 0, stream>>>(
        x, DMOD, wT, DMOD, b2qkv, nullptr, 0, nullptr, 0, u_bf, 3 * DMOD,
        ROWS, DMOD, 3 * DMOD, nullptr, nullptr, nullptr, psum, s1qkv);
    attn_fused<<<NCLS, 256, 0, stream>>>(u_bf, h_bf, plast);
    gemm_mfma<2, 64><<<dim3(4, 94), 256, 0, stream>>>(
        h_bf, DMOD, wT + LSo, DMOD, bo, x, DMOD, nullptr, 0, x, DMOD,
        ROWS, DMOD, DMOD, nullptr, nullptr, nullptr, psum, nullptr);
    gemm_mfma<5, 32><<<dim3(16, 94), 256, 0, stream>>>(
        x, DMOD, wT + LSo + (size_t)DMOD * DMOD, DMOD, b2ff1, nullptr, 0, nullptr, 0,
        u_bf, DFF, ROWS, DMOD, DFF, nullptr, nullptr, nullptr, psum, s1ff1);
    gemm_mfma<2, 64><<<dim3(4, 94), 256, 0, stream>>>(
        u_bf, DFF, wT + LSo + (size_t)DMOD * DMOD + (size_t)DMOD * DFF, DFF, b2,
        x, DMOD, nullptr, 0, x, DMOD, ROWS, DFF, DMOD,
        nullptr, nullptr, nullptr, psum, nullptr);
    // layer 1: full qkv (K,V needed for all rows; Q used only at qi=11)
    gemm_mfma<4, 32><<<dim3(12, 94), 256, 0, stream>>>(
        x, DMOD, wT + LS, DMOD, b2qkv + 3 * DMOD, nullptr, 0, nullptr, 0,
        u_bf, 3 * DMOD, ROWS, DMOD, 3 * DMOD, nullptr, nullptr, nullptr,
        psum, s1qkv + 3 * DMOD);
    attn_last<<<NCLS, 128, 0, stream>>>(u_bf, hl_bf);
    // compact Wo: xl = x[rows≡11] + hl @ Wo + bo   (M=1000; Rb strided picks rows n*12+11)
    gemm_mfma<2, 64><<<dim3(4, 8), 256, 0, stream>>>(
        hl_bf, DMOD, wT + LS + LSo, DMOD, bo + DMOD,
        x + 11 * DMOD, LSEQ * DMOD, nullptr, 0, xl_bf, DMOD,
        NCLS, DMOD, DMOD, nullptr, nullptr, nullptr, psum, nullptr);
    // compact FF1: u = gelu(LN2(xl) @ W1 + b1) (M=1000, psum compact from Wo)
    gemm_mfma<5, 32><<<dim3(16, 8), 256, 0, stream>>>(
        xl_bf, DMOD, wT + LS + LSo + (size_t)DMOD * DMOD, DMOD, b2ff1 + DFF,
        nullptr, 0, nullptr, 0, u_bf, DFF, NCLS, DMOD, DFF,
        nullptr, nullptr, nullptr, psum, s1ff1 + DFF);
    // compact FF2: xl = xl + u @ W2 + b2 (M=1000)
    gemm_mfma<2, 64><<<dim3(4, 8), 256, 0, stream>>>(
        u_bf, DFF, wT + LS + LSo + (size_t)DMOD * DMOD + (size_t)DMOD * DFF, DFF,
        b2 + DMOD, xl_bf, DMOD, nullptr, 0, xl_bf, DMOD,
        NCLS, DFF, DMOD, nullptr, nullptr, nullptr, nullptr, nullptr);

    // ======================= final head ===============================================
    final_prep2<<<70, 256, 0, stream>>>(images, img_bf, invi, tf_bf);
    // tf = xl @ tproj (compact A, M=1000)
    gemm_mfma<0, 64><<<dim3(4, 8), 256, 0, stream>>>(
        xl_bf, DMOD, tprojT, DMOD, nullptr, nullptr, 0, nullptr, 0,
        tf_bf, DMOD, NCLS, DMOD, DMOD, nullptr, nullptr, nullptr, nullptr, nullptr);
    rownorm_inv_bf16<<<NCLS, 256, 0, stream>>>(tf_bf, invt);
    // logits = exp(ls) * invi[m] * invt[n] * (img_bf @ tf_bf^T)
    gemm_mfma<3, 64><<<dim3(8, 2), 256, 0, stream>>>(
        img_bf, DMOD, tf_bf, DMOD, nullptr, nullptr, 0, out, NCLS, nullptr, 0,
        BIMG, DMOD, NCLS, invi, invt, lsp, nullptr, nullptr);
    attribution_kernel<<<PFX, 256, 0, stream>>>(attr, out + (size_t)BIMG * NCLS);
}